// Round 11
// baseline (6010.102 us; speedup 1.0000x reference)
//
#include <hip/hip_runtime.h>

// ResidualVQ: Q=4, N_EMBED=1024, DIM=256, B=8, S=2048 (fp32).
// out = [quantized 8*2048*256][indices-as-float 4*8*2048][losses 4]
//
// R11: bf16-MFMA prefilter + certified exact re-rank.
//  - approx dist via mfma_f32_16x16x32_bf16 (X,E -> bf16 RNE, fp32 accum)
//  - candidate set = { k : d~ <= d~min + tau }, tau = 2^-5*sqrt(a*bmax)+0.1
//    (rigorous bound: |d~ - d_np| <= 2*2^-7*||x||*||e|| + eps)
//  - candidates re-ranked with the FROZEN numpy fp32 pipeline (verified R4-R10):
//    a,b = AVX-512 pairwise sumsq; m = ascending-d single-acc fma chain;
//    dist = fl(fl(a - fl(2m)) + b); first-occurrence/lower-index tie-break.
//  - STE recursion op-for-op FROZEN (feeds next stage argmin).
#define QQ   4
#define NE   1024
#define DIMD 256
#define MM   16384
#define TM   16
#define NW   8      // waves per block (512 threads)
#define CAP  16     // candidate slots per row

typedef short v8s __attribute__((ext_vector_type(8)));   // 8 x bf16
typedef float v4f __attribute__((ext_vector_type(4)));

// ws layout (float offsets):
//  cb16  [QQ][NE][DIMD] ushort @ 0        (524,288 floats)
//  bK    [QQ][NE]              @ 524,288  (4,096)
//  bmaxI int[QQ]               @ 528,384  (4)
//  loss64 double[QQ]           @ 528,390  (8 floats; byte 2,113,560 %8==0)
//  resid [MM][DIMD]            @ 528,400  (4,194,304; 16B aligned)

__device__ __forceinline__ unsigned short f2bf(float f) {  // RNE fp32->bf16
  unsigned u = __float_as_uint(f);
  return (unsigned short)((u + 0x7FFFu + ((u >> 16) & 1u)) >> 16);
}

// numpy (AVX-512 dispatch) pairwise sum of squares of 256 contiguous f32 — FROZEN
__device__ __forceinline__ float np_sumsq_256(const float* __restrict__ v) {
  float blk[2];
  #pragma unroll
  for (int bi = 0; bi < 2; ++bi) {
    const float* p = v + bi * 128;
    float w[16];
    #pragma unroll
    for (int L = 0; L < 16; ++L) {
      float s0 = __fmul_rn(p[0 * 16 + L], p[0 * 16 + L]);
      float s1 = __fmul_rn(p[1 * 16 + L], p[1 * 16 + L]);
      float s2 = __fmul_rn(p[2 * 16 + L], p[2 * 16 + L]);
      float s3 = __fmul_rn(p[3 * 16 + L], p[3 * 16 + L]);
      float s4 = __fmul_rn(p[4 * 16 + L], p[4 * 16 + L]);
      float s5 = __fmul_rn(p[5 * 16 + L], p[5 * 16 + L]);
      float s6 = __fmul_rn(p[6 * 16 + L], p[6 * 16 + L]);
      float s7 = __fmul_rn(p[7 * 16 + L], p[7 * 16 + L]);
      w[L] = __fadd_rn(__fadd_rn(__fadd_rn(s0, s1), __fadd_rn(s2, s3)),
                       __fadd_rn(__fadd_rn(s4, s5), __fadd_rn(s6, s7)));
    }
    float u[8], t[4], r2[2];
    #pragma unroll
    for (int L = 0; L < 8; ++L) u[L] = __fadd_rn(w[L], w[L + 8]);
    #pragma unroll
    for (int L = 0; L < 4; ++L) t[L] = __fadd_rn(u[L], u[L + 4]);
    #pragma unroll
    for (int L = 0; L < 2; ++L) r2[L] = __fadd_rn(t[L], t[L + 2]);
    blk[bi] = __fadd_rn(r2[0], r2[1]);
  }
  return __fadd_rn(blk[0], blk[1]);
}

// frozen np distance for one (row,code): m = ascending-d single-acc fma chain
__device__ __forceinline__ float np_dist(const float* __restrict__ xp,
                                         const float* __restrict__ ep,
                                         float a, float b) {
  float m = 0.f;
  for (int d = 0; d < DIMD; ++d) m = fmaf(xp[d], ep[d], m);
  return __fadd_rn(__fsub_rn(a, __fmul_rn(2.0f, m)), b);
}

__global__ __launch_bounds__(256) void k_init(const float* __restrict__ x,
                                              float* __restrict__ resid,
                                              double* __restrict__ loss64,
                                              int* __restrict__ bmaxI) {
  size_t i = (size_t)blockIdx.x * blockDim.x + threadIdx.x;
  const size_t n4 = (size_t)MM * DIMD / 4;
  const float4* xs = (const float4*)x;
  float4* rd = (float4*)resid;
  for (size_t p = i; p < n4; p += (size_t)gridDim.x * blockDim.x) rd[p] = xs[p];
  if (i < QQ) { loss64[i] = 0.0; bmaxI[i] = 0; }
}

// convert all codebooks to bf16 (RNE): 1,048,576 elements, 4/thread
__global__ __launch_bounds__(256) void k_cb16(const float* __restrict__ cb,
                                              unsigned short* __restrict__ cb16) {
  int i = (blockIdx.x * 256 + threadIdx.x) * 4;
  float4 f = *(const float4*)(cb + i);
  unsigned short t[4] = {f2bf(f.x), f2bf(f.y), f2bf(f.z), f2bf(f.w)};
  *(short4*)(cb16 + i) = *(short4*)t;
}

// b_k (frozen np sumsq) + per-stage max (positive floats -> int-monotone)
__global__ __launch_bounds__(256) void k_b(const float* __restrict__ cb,
                                           float* __restrict__ bK,
                                           int* __restrict__ bmaxI) {
  int k = blockIdx.x * 256 + threadIdx.x;      // 0 .. QQ*NE-1
  float b = np_sumsq_256(cb + (size_t)k * DIMD);
  bK[k] = b;
  atomicMax(bmaxI + (k >> 10), __float_as_int(b));
}

// 512 threads = 8 waves; block = TM=16 rows x all 1024 codes.
// Wave w covers codes [w*128,(w+1)*128) as 8 16x16 MFMA col-tiles.
__global__ __launch_bounds__(512, 4) void k_stage(
    const unsigned short* __restrict__ cb16, // [NE][DIMD] bf16 for qi
    const float* __restrict__ bK,            // [NE] for qi
    const int*   __restrict__ bmaxp,         // &bmaxI[qi]
    const float* __restrict__ cb,            // [NE][DIMD] fp32 for qi
    const float* __restrict__ resid_r,       // == resid
    float* __restrict__ resid_w,             // == resid
    double* __restrict__ loss64,             // &loss64[qi]
    float* __restrict__ idx_out) {           // [MM] floats
  __shared__ unsigned short sX[TM][DIMD + 8];  // bf16 rows, +8 pad vs conflicts
  __shared__ float  av_s[TM];
  __shared__ float  candD[TM][NW];
  __shared__ float  thrS[TM];
  __shared__ int    cnt[TM];
  __shared__ int    candL[TM][CAP];
  __shared__ float  dcD[TM][CAP];
  __shared__ int    bcode[TM];
  __shared__ double lossW[NW];

  const int tid  = threadIdx.x;
  const int lane = tid & 63;
  const int wv   = tid >> 6;
  const int rowBase = blockIdx.x * TM;
  const float bmx = __int_as_float(*bmaxp);

  if (tid < TM) {
    av_s[tid] = np_sumsq_256(resid_r + (size_t)(rowBase + tid) * DIMD);  // FROZEN
    cnt[tid] = 0;
  }
  // stage rows as bf16 into LDS (RNE)
  {
    const int r = tid >> 5, d = (tid & 31) * 8;
    const float* rp = resid_r + (size_t)(rowBase + r) * DIMD + d;
    const float4 f0 = *(const float4*)rp;
    const float4 f1 = *(const float4*)(rp + 4);
    unsigned short t[8] = {f2bf(f0.x), f2bf(f0.y), f2bf(f0.z), f2bf(f0.w),
                           f2bf(f1.x), f2bf(f1.y), f2bf(f1.z), f2bf(f1.w)};
    *(v8s*)&sX[r][d] = *(v8s*)t;
  }
  __syncthreads();

  const int m16  = lane & 15;
  const int quad = lane >> 4;

  // MFMA: M~[row][code] for 8 col-tiles; A from LDS, B from cb16 (row-major)
  v4f acc[8];
  #pragma unroll
  for (int ct = 0; ct < 8; ++ct) acc[ct] = (v4f)(0.f);
  const unsigned short* bptr = cb16 + ((size_t)(wv * 128 + m16)) * DIMD + quad * 8;
  #pragma unroll
  for (int kc = 0; kc < 8; ++kc) {
    v8s afr = *(const v8s*)&sX[m16][kc * 32 + quad * 8];
    #pragma unroll
    for (int ct = 0; ct < 8; ++ct) {
      v8s bfr = *(const v8s*)(bptr + (size_t)ct * 16 * DIMD + kc * 32);
      acc[ct] = __builtin_amdgcn_mfma_f32_16x16x32_bf16(afr, bfr, acc[ct], 0, 0, 0);
    }
  }

  // approx dist in-place: d~ = a - 2*M~ + b   (D: row=quad*4+reg, col=m16)
  float av4[4];
  #pragma unroll
  for (int v = 0; v < 4; ++v) av4[v] = av_s[quad * 4 + v];
  #pragma unroll
  for (int ct = 0; ct < 8; ++ct) {
    const float bv = bK[wv * 128 + ct * 16 + m16];
    #pragma unroll
    for (int v = 0; v < 4; ++v) acc[ct][v] = av4[v] - 2.0f * acc[ct][v] + bv;
  }

  // per-row min: over ct, then across the 16 lanes of each quad
  float vmin[4];
  #pragma unroll
  for (int v = 0; v < 4; ++v) {
    vmin[v] = acc[0][v];
    #pragma unroll
    for (int ct = 1; ct < 8; ++ct) vmin[v] = fminf(vmin[v], acc[ct][v]);
    #pragma unroll
    for (int off = 1; off < 16; off <<= 1)
      vmin[v] = fminf(vmin[v], __shfl_xor(vmin[v], off, 64));
  }
  if (m16 == 0) {
    #pragma unroll
    for (int v = 0; v < 4; ++v) candD[quad * 4 + v][wv] = vmin[v];
  }
  __syncthreads();
  if (tid < TM) {
    float bd = candD[tid][0];
    #pragma unroll
    for (int w = 1; w < NW; ++w) bd = fminf(bd, candD[tid][w]);
    // certified margin: 2*2^-7*sqrt(a*bmax) needed; 2^-5*sqrt(.)+0.1 = 2x slack
    thrS[tid] = bd + 0.03125f * sqrtf(av_s[tid] * bmx) + 0.1f;
  }
  __syncthreads();

  // gather candidates
  #pragma unroll
  for (int ct = 0; ct < 8; ++ct) {
    const int code = wv * 128 + ct * 16 + m16;
    #pragma unroll
    for (int v = 0; v < 4; ++v) {
      const int row = quad * 4 + v;
      if (acc[ct][v] <= thrS[row]) {
        int pos = atomicAdd(&cnt[row], 1);
        if (pos < CAP) candL[row][pos] = code;
      }
    }
  }
  __syncthreads();

  // exact (frozen) distance per candidate: thread (r,ci)
  if (tid < TM * CAP) {
    const int r = tid >> 4, ci = tid & (CAP - 1);
    const int n = cnt[r] < CAP ? cnt[r] : CAP;
    if (ci < n) {
      const int code = candL[r][ci];
      dcD[r][ci] = np_dist(resid_r + (size_t)(rowBase + r) * DIMD,
                           cb + (size_t)code * DIMD, av_s[r], bK[code]);
    }
  }
  __syncthreads();
  if (tid < TM) {
    float bd = 3.4e38f;
    int bi = 0x7fffffff;
    if (cnt[tid] > CAP) {           // overflow fallback: exhaustive (never hit)
      const float* xp = resid_r + (size_t)(rowBase + tid) * DIMD;
      for (int code = 0; code < NE; ++code) {
        float s = np_dist(xp, cb + (size_t)code * DIMD, av_s[tid], bK[code]);
        if (s < bd) { bd = s; bi = code; }   // strict <: first occurrence
      }
    } else {
      for (int ci = 0; ci < cnt[tid]; ++ci) {
        float d = dcD[tid][ci];
        int code = candL[tid][ci];
        if (d < bd || (d == bd && code < bi)) { bd = d; bi = code; }
      }
    }
    bcode[tid] = bi;
    idx_out[rowBase + tid] = (float)bi;
  }
  __syncthreads();

  // STE update — FROZEN (feeds next stage argmin): t=fl(q-r); u=fl(r+t); r'=fl(r-u)
  const int r2 = tid >> 5;
  const int dd = (tid & 31) * 8;
  const int codeB = bcode[r2];
  const int row = rowBase + r2;
  double lsum = 0.0;
  #pragma unroll
  for (int h = 0; h < 2; ++h) {
    const int d = dd + h * 4;
    const float4 ev = *(const float4*)(cb + (size_t)codeB * DIMD + d);
    const float4 rv = *(const float4*)(resid_r + (size_t)row * DIMD + d);
    float t0 = __fsub_rn(ev.x, rv.x), u0 = __fadd_rn(rv.x, t0);
    float t1 = __fsub_rn(ev.y, rv.y), u1 = __fadd_rn(rv.y, t1);
    float t2 = __fsub_rn(ev.z, rv.z), u2 = __fadd_rn(rv.z, t2);
    float t3 = __fsub_rn(ev.w, rv.w), u3 = __fadd_rn(rv.w, t3);
    *(float4*)(resid_w + (size_t)row * DIMD + d) =
        make_float4(__fsub_rn(rv.x, u0), __fsub_rn(rv.y, u1),
                    __fsub_rn(rv.z, u2), __fsub_rn(rv.w, u3));
    lsum += (double)__fmul_rn(t0, t0) + (double)__fmul_rn(t1, t1) +
            (double)__fmul_rn(t2, t2) + (double)__fmul_rn(t3, t3);
  }
  #pragma unroll
  for (int off = 32; off; off >>= 1) lsum += __shfl_xor(lsum, off, 64);
  if (lane == 0) lossW[wv] = lsum;
  __syncthreads();
  if (tid == 0) {
    double s = 0.0;
    #pragma unroll
    for (int w = 0; w < NW; ++w) s += lossW[w];
    atomicAdd(loss64, s);
  }
}

// out0 = x - resid_final (fp32): diff vs np STE-sum ~1e-5 << threshold 20.48
__global__ __launch_bounds__(256) void k_final(const float* __restrict__ x,
                                               const float* __restrict__ resid,
                                               const double* __restrict__ loss64,
                                               float* __restrict__ out_q,
                                               float* __restrict__ out_loss) {
  size_t i = (size_t)blockIdx.x * blockDim.x + threadIdx.x;
  const size_t n4 = (size_t)MM * DIMD / 4;
  const float4* xs = (const float4*)x;
  const float4* rd = (const float4*)resid;
  float4* q = (float4*)out_q;
  for (size_t p = i; p < n4; p += (size_t)gridDim.x * blockDim.x) {
    float4 a = xs[p], b = rd[p];
    q[p] = make_float4(__fsub_rn(a.x, b.x), __fsub_rn(a.y, b.y),
                       __fsub_rn(a.z, b.z), __fsub_rn(a.w, b.w));
  }
  if (i < QQ) out_loss[i] = (float)(loss64[i] * (1.0 / (double)((size_t)MM * DIMD)));
}

extern "C" void kernel_launch(void* const* d_in, const int* in_sizes, int n_in,
                              void* d_out, int out_size, void* d_ws, size_t ws_size,
                              hipStream_t stream) {
  const float* x = (const float*)d_in[0];        // [8,2048,256]
  const float* cb = (const float*)d_in[1];       // [4,1024,256]
  float* ws = (float*)d_ws;
  unsigned short* cb16 = (unsigned short*)ws;    // 1,048,576 ushort
  float* bK = ws + 524288;
  int* bmaxI = (int*)(ws + 528384);
  double* loss64 = (double*)(ws + 528390);
  float* resid = ws + 528400;

  float* out = (float*)d_out;
  float* out_idx = out + (size_t)MM * DIMD;      // 4,194,304
  float* out_loss = out_idx + (size_t)QQ * MM;   // +65,536

  k_init<<<dim3(2048), dim3(256), 0, stream>>>(x, resid, loss64, bmaxI);
  k_cb16<<<dim3(1024), dim3(256), 0, stream>>>(cb, cb16);
  k_b<<<dim3(QQ * NE / 256), dim3(256), 0, stream>>>(cb, bK, bmaxI);
  for (int qi = 0; qi < QQ; ++qi) {
    k_stage<<<dim3(MM / TM), dim3(512), 0, stream>>>(
        cb16 + (size_t)qi * NE * DIMD, bK + (size_t)qi * NE, bmaxI + qi,
        cb + (size_t)qi * NE * DIMD, resid, resid, loss64 + qi,
        out_idx + (size_t)qi * MM);
  }
  k_final<<<dim3(2048), dim3(256), 0, stream>>>(x, resid, loss64, out, out_loss);
}

// Round 12
// 631.615 us; speedup vs baseline: 9.5155x; 9.5155x over previous
//
#include <hip/hip_runtime.h>

// ResidualVQ: Q=4, N_EMBED=1024, DIM=256, B=8, S=2048 (fp32).
// out = [quantized 8*2048*256][indices-as-float 4*8*2048][losses 4]
//
// R12: bf16-MFMA prefilter + certified exact re-rank (R11 structure), with the
// R11 straggler fixed: float4-pipelined exact distance (same frozen fma order)
// and a COOPERATIVE block-wide fallback for candidate-overflow rows (R11's
// single-lane exhaustive chain = 2.7-44ms straggler that emptied the GPU).
//  - approx dist via mfma_f32_16x16x32_bf16 (X,E -> bf16 RNE, fp32 accum)
//  - candidates = { k : d~ <= d~min + tau }, tau = 2^-5*sqrt(a*bmax)+0.1
//    (rigorous: |d~ - d_np| <= 2*2^-8*||x||*||e|| + eps; 8x slack)
//  - re-rank with FROZEN numpy fp32 pipeline (verified R4-R11, idx bit-exact):
//    a,b = AVX-512 pairwise sumsq; m = ascending-d single-acc fma chain;
//    dist = fl(fl(a - fl(2m)) + b); tie -> lower index.
//  - STE recursion op-for-op FROZEN (feeds next stage argmin).
#define QQ   4
#define NE   1024
#define DIMD 256
#define MM   16384
#define TM   16
#define NW   8      // waves per block (512 threads)
#define CAP  32     // candidate slots per row (TM*CAP == 512)

typedef short v8s __attribute__((ext_vector_type(8)));   // 8 x bf16
typedef float v4f __attribute__((ext_vector_type(4)));

// ws layout (float offsets):
//  cb16  [QQ][NE][DIMD] ushort @ 0        (524,288 floats)
//  bK    [QQ][NE]              @ 524,288  (4,096)
//  bmaxI int[QQ]               @ 528,384  (4)
//  loss64 double[QQ]           @ 528,390  (byte 2,113,560 %8==0)
//  resid [MM][DIMD]            @ 528,400  (4,194,304; 16B aligned)

__device__ __forceinline__ unsigned short f2bf(float f) {  // RNE fp32->bf16
  unsigned u = __float_as_uint(f);
  return (unsigned short)((u + 0x7FFFu + ((u >> 16) & 1u)) >> 16);
}

// numpy (AVX-512 dispatch) pairwise sum of squares of 256 contiguous f32 — FROZEN
__device__ __forceinline__ float np_sumsq_256(const float* __restrict__ v) {
  float blk[2];
  #pragma unroll
  for (int bi = 0; bi < 2; ++bi) {
    const float* p = v + bi * 128;
    float w[16];
    #pragma unroll
    for (int L = 0; L < 16; ++L) {
      float s0 = __fmul_rn(p[0 * 16 + L], p[0 * 16 + L]);
      float s1 = __fmul_rn(p[1 * 16 + L], p[1 * 16 + L]);
      float s2 = __fmul_rn(p[2 * 16 + L], p[2 * 16 + L]);
      float s3 = __fmul_rn(p[3 * 16 + L], p[3 * 16 + L]);
      float s4 = __fmul_rn(p[4 * 16 + L], p[4 * 16 + L]);
      float s5 = __fmul_rn(p[5 * 16 + L], p[5 * 16 + L]);
      float s6 = __fmul_rn(p[6 * 16 + L], p[6 * 16 + L]);
      float s7 = __fmul_rn(p[7 * 16 + L], p[7 * 16 + L]);
      w[L] = __fadd_rn(__fadd_rn(__fadd_rn(s0, s1), __fadd_rn(s2, s3)),
                       __fadd_rn(__fadd_rn(s4, s5), __fadd_rn(s6, s7)));
    }
    float u[8], t[4], r2[2];
    #pragma unroll
    for (int L = 0; L < 8; ++L) u[L] = __fadd_rn(w[L], w[L + 8]);
    #pragma unroll
    for (int L = 0; L < 4; ++L) t[L] = __fadd_rn(u[L], u[L + 4]);
    #pragma unroll
    for (int L = 0; L < 2; ++L) r2[L] = __fadd_rn(t[L], t[L + 2]);
    blk[bi] = __fadd_rn(r2[0], r2[1]);
  }
  return __fadd_rn(blk[0], blk[1]);
}

// frozen np distance, float4-load pipelined (IDENTICAL fma sequence/order)
__device__ __forceinline__ float np_dist_f4(const float* __restrict__ xp,
                                            const float* __restrict__ ep,
                                            float a, float b) {
  float m = 0.f;
  #pragma unroll 16
  for (int d4 = 0; d4 < DIMD / 4; ++d4) {
    const float4 xv = *(const float4*)(xp + d4 * 4);
    const float4 ev = *(const float4*)(ep + d4 * 4);
    m = fmaf(xv.x, ev.x, m);
    m = fmaf(xv.y, ev.y, m);
    m = fmaf(xv.z, ev.z, m);
    m = fmaf(xv.w, ev.w, m);
  }
  return __fadd_rn(__fsub_rn(a, __fmul_rn(2.0f, m)), b);
}

__global__ __launch_bounds__(256) void k_init(const float* __restrict__ x,
                                              float* __restrict__ resid,
                                              double* __restrict__ loss64,
                                              int* __restrict__ bmaxI) {
  size_t i = (size_t)blockIdx.x * blockDim.x + threadIdx.x;
  const size_t n4 = (size_t)MM * DIMD / 4;
  const float4* xs = (const float4*)x;
  float4* rd = (float4*)resid;
  for (size_t p = i; p < n4; p += (size_t)gridDim.x * blockDim.x) rd[p] = xs[p];
  if (i < QQ) { loss64[i] = 0.0; bmaxI[i] = 0; }
}

// convert all codebooks to bf16 (RNE): 1,048,576 elements, 4/thread
__global__ __launch_bounds__(256) void k_cb16(const float* __restrict__ cb,
                                              unsigned short* __restrict__ cb16) {
  int i = (blockIdx.x * 256 + threadIdx.x) * 4;
  float4 f = *(const float4*)(cb + i);
  unsigned short t[4] = {f2bf(f.x), f2bf(f.y), f2bf(f.z), f2bf(f.w)};
  *(short4*)(cb16 + i) = *(short4*)t;
}

// b_k (frozen np sumsq) + per-stage max (positive floats -> int-monotone)
__global__ __launch_bounds__(256) void k_b(const float* __restrict__ cb,
                                           float* __restrict__ bK,
                                           int* __restrict__ bmaxI) {
  int k = blockIdx.x * 256 + threadIdx.x;      // 0 .. QQ*NE-1
  float b = np_sumsq_256(cb + (size_t)k * DIMD);
  bK[k] = b;
  atomicMax(bmaxI + (k >> 10), __float_as_int(b));
}

// 512 threads = 8 waves; block = TM=16 rows x all 1024 codes.
// Wave w covers codes [w*128,(w+1)*128) as 8 16x16 MFMA col-tiles.
__global__ __launch_bounds__(512, 4) void k_stage(
    const unsigned short* __restrict__ cb16, // [NE][DIMD] bf16 for qi
    const float* __restrict__ bK,            // [NE] for qi
    const int*   __restrict__ bmaxp,         // &bmaxI[qi]
    const float* __restrict__ cb,            // [NE][DIMD] fp32 for qi
    const float* __restrict__ resid_r,       // == resid
    float* __restrict__ resid_w,             // == resid
    double* __restrict__ loss64,             // &loss64[qi]
    float* __restrict__ idx_out) {           // [MM] floats
  __shared__ unsigned short sX[TM][DIMD + 8];  // bf16 rows, +8 pad vs conflicts
  __shared__ float  av_s[TM];
  __shared__ float  candD[TM][NW];
  __shared__ float  thrS[TM];
  __shared__ int    cnt[TM];
  __shared__ int    candL[TM][CAP];
  __shared__ float  dcD[TM][CAP];
  __shared__ int    bcode[TM];
  __shared__ float  fwD[NW];
  __shared__ int    fwI[NW];
  __shared__ double lossW[NW];

  const int tid  = threadIdx.x;
  const int lane = tid & 63;
  const int wv   = tid >> 6;
  const int rowBase = blockIdx.x * TM;
  const float bmx = __int_as_float(*bmaxp);

  if (tid < TM) {
    av_s[tid] = np_sumsq_256(resid_r + (size_t)(rowBase + tid) * DIMD);  // FROZEN
    cnt[tid] = 0;
  }
  // stage rows as bf16 into LDS (RNE)
  {
    const int r = tid >> 5, d = (tid & 31) * 8;
    const float* rp = resid_r + (size_t)(rowBase + r) * DIMD + d;
    const float4 f0 = *(const float4*)rp;
    const float4 f1 = *(const float4*)(rp + 4);
    unsigned short t[8] = {f2bf(f0.x), f2bf(f0.y), f2bf(f0.z), f2bf(f0.w),
                           f2bf(f1.x), f2bf(f1.y), f2bf(f1.z), f2bf(f1.w)};
    *(v8s*)&sX[r][d] = *(v8s*)t;
  }
  __syncthreads();

  const int m16  = lane & 15;
  const int quad = lane >> 4;

  // MFMA: M~[row][code] for 8 col-tiles; A from LDS, B from cb16 (row-major)
  v4f acc[8];
  #pragma unroll
  for (int ct = 0; ct < 8; ++ct) acc[ct] = (v4f)(0.f);
  const unsigned short* bptr = cb16 + ((size_t)(wv * 128 + m16)) * DIMD + quad * 8;
  #pragma unroll
  for (int kc = 0; kc < 8; ++kc) {
    v8s afr = *(const v8s*)&sX[m16][kc * 32 + quad * 8];
    #pragma unroll
    for (int ct = 0; ct < 8; ++ct) {
      v8s bfr = *(const v8s*)(bptr + (size_t)ct * 16 * DIMD + kc * 32);
      acc[ct] = __builtin_amdgcn_mfma_f32_16x16x32_bf16(afr, bfr, acc[ct], 0, 0, 0);
    }
  }

  // approx dist in-place: d~ = a - 2*M~ + b   (D: row=quad*4+reg, col=m16)
  float av4[4];
  #pragma unroll
  for (int v = 0; v < 4; ++v) av4[v] = av_s[quad * 4 + v];
  #pragma unroll
  for (int ct = 0; ct < 8; ++ct) {
    const float bv = bK[wv * 128 + ct * 16 + m16];
    #pragma unroll
    for (int v = 0; v < 4; ++v) acc[ct][v] = av4[v] - 2.0f * acc[ct][v] + bv;
  }

  // per-row min: over ct, then across the 16 lanes of each quad
  float vmin[4];
  #pragma unroll
  for (int v = 0; v < 4; ++v) {
    vmin[v] = acc[0][v];
    #pragma unroll
    for (int ct = 1; ct < 8; ++ct) vmin[v] = fminf(vmin[v], acc[ct][v]);
    #pragma unroll
    for (int off = 1; off < 16; off <<= 1)
      vmin[v] = fminf(vmin[v], __shfl_xor(vmin[v], off, 64));
  }
  if (m16 == 0) {
    #pragma unroll
    for (int v = 0; v < 4; ++v) candD[quad * 4 + v][wv] = vmin[v];
  }
  __syncthreads();
  if (tid < TM) {
    float bd = candD[tid][0];
    #pragma unroll
    for (int w = 1; w < NW; ++w) bd = fminf(bd, candD[tid][w]);
    // certified margin: 2*2^-8*sqrt(a*bmax) needed; 2^-5*sqrt(.)+0.1 = 8x slack
    thrS[tid] = bd + 0.03125f * sqrtf(av_s[tid] * bmx) + 0.1f;
  }
  __syncthreads();

  // gather candidates
  #pragma unroll
  for (int ct = 0; ct < 8; ++ct) {
    const int code = wv * 128 + ct * 16 + m16;
    #pragma unroll
    for (int v = 0; v < 4; ++v) {
      const int row = quad * 4 + v;
      if (acc[ct][v] <= thrS[row]) {
        int pos = atomicAdd(&cnt[row], 1);
        if (pos < CAP) candL[row][pos] = code;
      }
    }
  }
  __syncthreads();

  // exact (frozen) distance per candidate: one thread per (row, slot)
  {
    const int r = tid >> 5, ci = tid & (CAP - 1);
    const int n = (cnt[r] <= CAP) ? cnt[r] : 0;   // overflow rows -> fallback
    if (ci < n) {
      const int code = candL[r][ci];
      dcD[r][ci] = np_dist_f4(resid_r + (size_t)(rowBase + r) * DIMD,
                              cb + (size_t)code * DIMD, av_s[r], bK[code]);
    }
  }
  __syncthreads();

  // cooperative fallback for overflow rows (rare): 2 codes/thread, exact
  for (int r = 0; r < TM; ++r) {
    if (cnt[r] > CAP) {
      const float* xp = resid_r + (size_t)(rowBase + r) * DIMD;
      const float a = av_s[r];
      float d1 = np_dist_f4(xp, cb + (size_t)tid * DIMD, a, bK[tid]);
      float d2 = np_dist_f4(xp, cb + (size_t)(tid + 512) * DIMD, a, bK[tid + 512]);
      int i1 = tid;
      if (d2 < d1) { d1 = d2; i1 = tid + 512; }   // strict <: lower idx on tie
      #pragma unroll
      for (int off = 32; off; off >>= 1) {
        float vd = __shfl_xor(d1, off, 64);
        int vi = __shfl_xor(i1, off, 64);
        if (vd < d1 || (vd == d1 && vi < i1)) { d1 = vd; i1 = vi; }
      }
      if (lane == 0) { fwD[wv] = d1; fwI[wv] = i1; }
      __syncthreads();
      if (tid == 0) {
        float bd = fwD[0];
        int bi = fwI[0];
        #pragma unroll
        for (int w = 1; w < NW; ++w) {
          if (fwD[w] < bd || (fwD[w] == bd && fwI[w] < bi)) { bd = fwD[w]; bi = fwI[w]; }
        }
        bcode[r] = bi;
      }
      __syncthreads();
    }
  }

  if (tid < TM) {
    if (cnt[tid] <= CAP) {
      float bd = 3.4e38f;
      int bi = 0x7fffffff;
      for (int ci = 0; ci < cnt[tid]; ++ci) {
        float d = dcD[tid][ci];
        int code = candL[tid][ci];
        if (d < bd || (d == bd && code < bi)) { bd = d; bi = code; }
      }
      bcode[tid] = bi;
    }
    idx_out[rowBase + tid] = (float)bcode[tid];
  }
  __syncthreads();

  // STE update — FROZEN (feeds next stage argmin): t=fl(q-r); u=fl(r+t); r'=fl(r-u)
  const int r2 = tid >> 5;
  const int dd = (tid & 31) * 8;
  const int codeB = bcode[r2];
  const int row = rowBase + r2;
  double lsum = 0.0;
  #pragma unroll
  for (int h = 0; h < 2; ++h) {
    const int d = dd + h * 4;
    const float4 ev = *(const float4*)(cb + (size_t)codeB * DIMD + d);
    const float4 rv = *(const float4*)(resid_r + (size_t)row * DIMD + d);
    float t0 = __fsub_rn(ev.x, rv.x), u0 = __fadd_rn(rv.x, t0);
    float t1 = __fsub_rn(ev.y, rv.y), u1 = __fadd_rn(rv.y, t1);
    float t2 = __fsub_rn(ev.z, rv.z), u2 = __fadd_rn(rv.z, t2);
    float t3 = __fsub_rn(ev.w, rv.w), u3 = __fadd_rn(rv.w, t3);
    *(float4*)(resid_w + (size_t)row * DIMD + d) =
        make_float4(__fsub_rn(rv.x, u0), __fsub_rn(rv.y, u1),
                    __fsub_rn(rv.z, u2), __fsub_rn(rv.w, u3));
    lsum += (double)__fmul_rn(t0, t0) + (double)__fmul_rn(t1, t1) +
            (double)__fmul_rn(t2, t2) + (double)__fmul_rn(t3, t3);
  }
  #pragma unroll
  for (int off = 32; off; off >>= 1) lsum += __shfl_xor(lsum, off, 64);
  if (lane == 0) lossW[wv] = lsum;
  __syncthreads();
  if (tid == 0) {
    double s = 0.0;
    #pragma unroll
    for (int w = 0; w < NW; ++w) s += lossW[w];
    atomicAdd(loss64, s);
  }
}

// out0 = x - resid_final (fp32): diff vs np STE-sum ~1e-5 << threshold 20.48
__global__ __launch_bounds__(256) void k_final(const float* __restrict__ x,
                                               const float* __restrict__ resid,
                                               const double* __restrict__ loss64,
                                               float* __restrict__ out_q,
                                               float* __restrict__ out_loss) {
  size_t i = (size_t)blockIdx.x * blockDim.x + threadIdx.x;
  const size_t n4 = (size_t)MM * DIMD / 4;
  const float4* xs = (const float4*)x;
  const float4* rd = (const float4*)resid;
  float4* q = (float4*)out_q;
  for (size_t p = i; p < n4; p += (size_t)gridDim.x * blockDim.x) {
    float4 a = xs[p], b = rd[p];
    q[p] = make_float4(__fsub_rn(a.x, b.x), __fsub_rn(a.y, b.y),
                       __fsub_rn(a.z, b.z), __fsub_rn(a.w, b.w));
  }
  if (i < QQ) out_loss[i] = (float)(loss64[i] * (1.0 / (double)((size_t)MM * DIMD)));
}

extern "C" void kernel_launch(void* const* d_in, const int* in_sizes, int n_in,
                              void* d_out, int out_size, void* d_ws, size_t ws_size,
                              hipStream_t stream) {
  const float* x = (const float*)d_in[0];        // [8,2048,256]
  const float* cb = (const float*)d_in[1];       // [4,1024,256]
  float* ws = (float*)d_ws;
  unsigned short* cb16 = (unsigned short*)ws;    // 1,048,576 ushort
  float* bK = ws + 524288;
  int* bmaxI = (int*)(ws + 528384);
  double* loss64 = (double*)(ws + 528390);
  float* resid = ws + 528400;

  float* out = (float*)d_out;
  float* out_idx = out + (size_t)MM * DIMD;      // 4,194,304
  float* out_loss = out_idx + (size_t)QQ * MM;   // +65,536

  k_init<<<dim3(2048), dim3(256), 0, stream>>>(x, resid, loss64, bmaxI);
  k_cb16<<<dim3(1024), dim3(256), 0, stream>>>(cb, cb16);
  k_b<<<dim3(QQ * NE / 256), dim3(256), 0, stream>>>(cb, bK, bmaxI);
  for (int qi = 0; qi < QQ; ++qi) {
    k_stage<<<dim3(MM / TM), dim3(512), 0, stream>>>(
        cb16 + (size_t)qi * NE * DIMD, bK + (size_t)qi * NE, bmaxI + qi,
        cb + (size_t)qi * NE * DIMD, resid, resid, loss64 + qi,
        out_idx + (size_t)qi * MM);
  }
  k_final<<<dim3(2048), dim3(256), 0, stream>>>(x, resid, loss64, out, out_loss);
}